// Round 4
// baseline (225.806 us; speedup 1.0000x reference)
//
#include <hip/hip_runtime.h>
#include <hip/hip_bf16.h>

// MHA: B=2 S=2048 D=768 H=12 DK=64. fp32 in/out; bf16 MFMA internally.
#define B_  2
#define S_  2048
#define D_  768
#define H_  12
#define DK_ 64
#define NX_ (B_*S_*D_)      // 3145728 activation elements
#define NW_ (D_*D_)         // 589824 weight elements
#define CSC 0.18033688011112042f   // 0.125 * log2(e), baked into wq/bq

typedef __attribute__((ext_vector_type(8))) short  bf16x8;
typedef __attribute__((ext_vector_type(4))) float  f32x4;

__device__ __forceinline__ unsigned short f2bf(float f) {
    unsigned int u = __float_as_uint(f);
    u += 0x7fffu + ((u >> 16) & 1u);   // RNE
    return (unsigned short)(u >> 16);
}

// pack two fp32 -> two bf16 (+0x8000 then hi16) in 3 VALU ops
__device__ __forceinline__ unsigned pack_bf2(float a, float b) {
    const unsigned ua = __float_as_uint(a) + 0x8000u;
    const unsigned ub = __float_as_uint(b) + 0x8000u;
    return __builtin_amdgcn_perm(ub, ua, 0x07060302u);
}

__device__ __forceinline__ void async_cp16(const unsigned short* g,
                                           const unsigned short* lds_uniform_base) {
    __builtin_amdgcn_global_load_lds(
        (const __attribute__((address_space(1))) unsigned int*)(uintptr_t)g,
        (__attribute__((address_space(3))) unsigned int*)(unsigned int)(uintptr_t)lds_uniform_base,
        16, 0, 0);
}

// ---------------------------------------------------------------------------
// Fused fp32->bf16 cvt, xor-swizzled per 64-el k-block (group g8 -> g8^(n&7)).
// 16 elements/thread. 1D grid: 3*768 activation blocks + 4*144 weight blocks.
// ---------------------------------------------------------------------------
struct CvtArgs { const float* s[7]; };

__global__ __launch_bounds__(256) void cvt_all(CvtArgs a,
                                               unsigned short* __restrict__ Xsw,
                                               unsigned short* __restrict__ Wsw) {
    const int bx = blockIdx.x;
    int y, inner;
    if (bx < 2304) { y = bx / 768;             inner = bx % 768; }
    else           { y = 3 + (bx - 2304) / 144; inner = (bx - 2304) % 144; }
    const int idx = inner * 256 + threadIdx.x;
    const int n  = idx / 48;
    const int g2 = idx % 48;                  // 16-el group in row
    const float* src = a.s[y] + (long)n * D_ + g2 * 16;
    const float zs = (y == 3) ? CSC : 1.0f;
    unsigned short o[16];
#pragma unroll
    for (int i = 0; i < 4; i++) {
        const float4 f = *(const float4*)(src + i * 4);
        o[i*4+0] = f2bf(f.x*zs); o[i*4+1] = f2bf(f.y*zs);
        o[i*4+2] = f2bf(f.z*zs); o[i*4+3] = f2bf(f.w*zs);
    }
    unsigned short* dst = (y >= 3) ? (Wsw + (long)(y - 3) * NW_ + (long)n * D_)
                                   : (Xsw + (long)y * NX_ + (long)n * D_);
    const int key = n & 7;
#pragma unroll
    for (int h = 0; h < 2; h++) {
        const int g8 = g2 * 2 + h;
        const int kdst = (g8 >> 3) * 64 + (((g8 & 7) ^ key) * 8);
        *(uint4*)(dst + kdst) = *(const uint4*)&o[h * 8];
    }
}

// ---------------------------------------------------------------------------
// Fused QKV projection. grid(32, 18): y -> zz = y/6, nb = y%6. Tile 128x128,
// BK=64, 4 waves 2x2. Both operands async-staged from swizzled bf16 global.
// launch_bounds(256,3): all 576 blocks resident (no tail round).
// Outputs: Q/K [bh][s][dk]; V transposed+pi-permuted [bh][dk][s'].
// ---------------------------------------------------------------------------
struct QkvArgs { const float* bias[3]; unsigned short* out[3]; };

__global__ __launch_bounds__(256, 3) void gemm_qkv(QkvArgs args,
                                                   const unsigned short* __restrict__ Xsw,
                                                   const unsigned short* __restrict__ Wsw) {
    __shared__ __align__(16) unsigned short smem[17408];
    unsigned short* As = smem;           // [128][64] swizzled
    unsigned short* Bs = smem + 8192;    // [128][64] swizzled

    const int t    = threadIdx.x;
    const int wave = t >> 6;
    const int lane = t & 63;
    const int l16  = lane & 15;
    const int quad = lane >> 4;
    const int wm   = wave >> 1, wn = wave & 1;
    const int m0   = blockIdx.x * 128;
    const int zz   = blockIdx.y / 6;
    const int nb   = blockIdx.y % 6;
    const int n0   = nb * 128;

    const unsigned short* Ap = Xsw + (long)zz * NX_;
    const unsigned short* Wp = Wsw + (long)zz * NW_;

    f32x4 acc[4][4];
#pragma unroll
    for (int s = 0; s < 4; s++)
#pragma unroll
        for (int j = 0; j < 4; j++) acc[s][j] = (f32x4){0.f, 0.f, 0.f, 0.f};

    const int lrow = lane >> 3;
    const int lcg  = lane & 7;

    for (int k0 = 0; k0 < D_; k0 += 64) {
        __syncthreads();
#pragma unroll
        for (int i = 0; i < 4; i++) {
            const int chunk = wave * 4 + i;
            async_cp16(Ap + (long)(m0 + chunk * 8 + lrow) * D_ + k0 + lcg * 8,
                       As + chunk * 512);
        }
#pragma unroll
        for (int i = 0; i < 4; i++) {
            const int chunk = wave * 4 + i;
            async_cp16(Wp + (long)(n0 + chunk * 8 + lrow) * D_ + k0 + lcg * 8,
                       Bs + chunk * 512);
        }
        __syncthreads();
#pragma unroll
        for (int ks = 0; ks < 2; ks++) {
            const int cg = ks * 4 + quad;
            bf16x8 af[4], bf[4];
#pragma unroll
            for (int s = 0; s < 4; s++) {
                const int r = wm * 64 + s * 16 + l16;
                af[s] = *(const bf16x8*)&As[r * 64 + ((cg ^ (r & 7)) * 8)];
            }
#pragma unroll
            for (int j = 0; j < 4; j++) {
                const int r = wn * 64 + j * 16 + l16;
                bf[j] = *(const bf16x8*)&Bs[r * 64 + ((cg ^ (r & 7)) * 8)];
            }
#pragma unroll
            for (int s = 0; s < 4; s++)
#pragma unroll
                for (int j = 0; j < 4; j++)
                    acc[s][j] = __builtin_amdgcn_mfma_f32_16x16x32_bf16(af[s], bf[j], acc[s][j], 0, 0, 0);
        }
    }
    __syncthreads();

    const int b     = m0 >> 11;
    const int sbase = m0 & (S_ - 1);
    const float zs  = (zz == 0) ? CSC : 1.0f;
    float bv[4];
#pragma unroll
    for (int j = 0; j < 4; j++) bv[j] = args.bias[zz][n0 + wn * 64 + j * 16 + l16] * zs;

    if (zz < 2) {
        unsigned short* Ls = smem;       // [128][136]
#pragma unroll
        for (int s = 0; s < 4; s++)
#pragma unroll
            for (int j = 0; j < 4; j++)
#pragma unroll
                for (int r = 0; r < 4; r++)
                    Ls[(wm * 64 + s * 16 + quad * 4 + r) * 136 + wn * 64 + j * 16 + l16] =
                        f2bf(acc[s][j][r] + bv[j]);
        __syncthreads();
        const int row  = t >> 1;
        const int half = t & 1;
        unsigned short* Op = args.out[zz];
#pragma unroll
        for (int i = 0; i < 8; i++) {
            const int col  = half * 64 + i * 8;
            const int head = nb * 2 + half;
            const uint4 v = *(const uint4*)&Ls[row * 136 + col];
            *(uint4*)(Op + ((long)(b * H_ + head) * S_ + sbase + row) * DK_ + (col & 63)) = v;
        }
    } else {
        unsigned short* Ls = smem;       // [2][64][136]
#pragma unroll
        for (int s = 0; s < 4; s++)
#pragma unroll
            for (int j = 0; j < 4; j++)
#pragma unroll
                for (int r = 0; r < 4; r++) {
                    const int dk  = j * 16 + l16;
                    const int pos = wm * 64 + (quad * 4 + r) * 4 + s;   // pi-permute
                    Ls[wn * 8704 + dk * 136 + pos] = f2bf(acc[s][j][r] + bv[j]);
                }
        __syncthreads();
        const int rowIdx = t >> 1;
        const int hh = rowIdx >> 6, dk = rowIdx & 63;
        const int half = t & 1;
        unsigned short* Op = args.out[2];
#pragma unroll
        for (int i = 0; i < 8; i++) {
            const int col = half * 64 + i * 8;
            const uint4 v = *(const uint4*)&Ls[hh * 8704 + dk * 136 + col];
            const int head = nb * 2 + hh;
            *(uint4*)(Op + ((long)(b * H_ + head) * DK_ + dk) * S_ + sbase + col) = v;
        }
    }
}

// ---------------------------------------------------------------------------
// Flash attention v3: LDS-pipe optimization of the proven R7 structure.
//  - 128-row q-tiles, 4 waves, each wave owns 32 q rows (2 row-blocks):
//    the 16 K/V b128 fragment reads per iteration now feed 32 MFMAs (was 16)
//    -> LDS read bytes per MAC halved.
//  - K/V/P tiles are [64][64] XOR-swizzled (16B chunk ^= row&7) instead of
//    [64][72] padded: removes the 7.1M bank-conflict cycles (~11.6 us/CU).
//  - 1D grid 384, bh = bid%24 (24%8==0 -> each head pinned to one XCD L2).
//  - Same per-iteration shape as the proven kernel: reg-prefetch rolling
//    pointers, double-buffered K/V, one barrier/iter, pi-permuted P/V,
//    no-max softmax (scale baked into Q).
//  - Epilogue: O-swizzle and global-store swizzle share key=row&7, so the
//    copy-out is a straight physical-chunk copy.
// ---------------------------------------------------------------------------
__global__ __launch_bounds__(256, 2) void attn_kernel(
    const unsigned short* __restrict__ Q, const unsigned short* __restrict__ K,
    const unsigned short* __restrict__ Vt, unsigned short* __restrict__ Ao)
{
    const int t    = threadIdx.x;
    const int wave = t >> 6;
    const int lane = t & 63;
    const int l16  = lane & 15;
    const int quad = lane >> 4;
    const int bid  = blockIdx.x;        // 384 blocks, 1D
    const int bh    = bid % 24;         // XCD = bid % 8 -> head-local L2
    const int qtile = bid / 24;         // 16 tiles of 128 rows

    const unsigned short* Qp = Q  + (long)bh * S_ * DK_;
    const unsigned short* Kp = K  + (long)bh * S_ * DK_;
    const unsigned short* Vp = Vt + (long)bh * DK_ * S_;

    __shared__ __align__(16) unsigned short smem[24576];   // 48 KB
    // Ks dbuf @0 [2][64][64]sw, Vs dbuf @8192, Ps @16384 [128][64]sw
    unsigned short* Ps = smem + 16384;

    // per-lane swizzle keys
    const int fkey = l16 & 7;                       // frag-read key (row = *16 + l16)
    const int fo0  = (((0 * 4 + quad) ^ fkey) * 8); // ks=0 chunk offset
    const int fo1  = (((1 * 4 + quad) ^ fkey) * 8); // ks=1 chunk offset

    // Q fragments: 2 row-blocks x 2 k-slices
    bf16x8 qf[2][2];
#pragma unroll
    for (int rb = 0; rb < 2; rb++) {
        const long qoff = (long)(qtile * 128 + wave * 32 + rb * 16 + l16) * DK_ + quad * 8;
        qf[rb][0] = *(const bf16x8*)(Qp + qoff);
        qf[rb][1] = *(const bf16x8*)(Qp + qoff + 32);
    }

    // staging: thread -> row t>>2 (0..63), chunk pair 2*(t&3), 2*(t&3)+1
    const int srow = t >> 2;
    const int sc2  = t & 3;
    const int skey = srow & 7;
    const int sA   = srow * 64 + (((2 * sc2)     ^ skey) * 8);
    const int sB   = srow * 64 + (((2 * sc2 + 1) ^ skey) * 8);
    uint4 kreg[2], vreg[2];
    const unsigned short* gk = Kp + (long)srow * DK_ + sc2 * 16;
    const unsigned short* gv = Vp + (long)srow * S_ + sc2 * 16;
    kreg[0] = *(const uint4*)gk;  kreg[1] = *(const uint4*)(gk + 8);
    vreg[0] = *(const uint4*)gv;  vreg[1] = *(const uint4*)(gv + 8);
    gk += 64 * DK_;  gv += 64;
    *(uint4*)&smem[sA]        = kreg[0];
    *(uint4*)&smem[sB]        = kreg[1];
    *(uint4*)&smem[8192 + sA] = vreg[0];
    *(uint4*)&smem[8192 + sB] = vreg[1];

    f32x4 oacc[2][4];
#pragma unroll
    for (int rb = 0; rb < 2; rb++)
#pragma unroll
        for (int j = 0; j < 4; j++) oacc[rb][j] = (f32x4){0.f, 0.f, 0.f, 0.f};
    float lsum[2][4] = {{0.f,0.f,0.f,0.f},{0.f,0.f,0.f,0.f}};

    for (int it = 0; it < 32; ++it) {
        const int co = (it & 1) * 4096;          // current buffer offset
        const int no = 4096 - co;                // next buffer offset
        __syncthreads();                 // prev-iter commits visible
        const unsigned short* Ks = smem + co;
        const unsigned short* Vs = smem + 8192 + co;

        if (it < 31) {                   // prefetch next tile into registers
            kreg[0] = *(const uint4*)gk;  kreg[1] = *(const uint4*)(gk + 8);
            vreg[0] = *(const uint4*)gv;  vreg[1] = *(const uint4*)(gv + 8);
            gk += 64 * DK_;  gv += 64;
        }

        // S = Q K^T + softmax numerator, per row-block
#pragma unroll
        for (int rb = 0; rb < 2; rb++) {
            f32x4 sacc[4];
#pragma unroll
            for (int j = 0; j < 4; j++) sacc[j] = (f32x4){0.f, 0.f, 0.f, 0.f};
#pragma unroll
            for (int j = 0; j < 4; j++) {
                const bf16x8 bf0 = *(const bf16x8*)&Ks[(j * 16 + l16) * 64 + fo0];
                sacc[j] = __builtin_amdgcn_mfma_f32_16x16x32_bf16(qf[rb][0], bf0, sacc[j], 0, 0, 0);
                const bf16x8 bf1 = *(const bf16x8*)&Ks[(j * 16 + l16) * 64 + fo1];
                sacc[j] = __builtin_amdgcn_mfma_f32_16x16x32_bf16(qf[rb][1], bf1, sacc[j], 0, 0, 0);
            }
            // p = exp2(s); packed b64 P-stores, pi-permuted cols, swizzled chunks
#pragma unroll
            for (int r = 0; r < 4; r++) {
                const float p0 = exp2f(sacc[0][r]);
                const float p1 = exp2f(sacc[1][r]);
                const float p2 = exp2f(sacc[2][r]);
                const float p3 = exp2f(sacc[3][r]);
                lsum[rb][r] += (p0 + p1) + (p2 + p3);
                uint2 pk = {pack_bf2(p0, p1), pack_bf2(p2, p3)};
                const int prow = wave * 32 + rb * 16 + quad * 4 + r;
                const int padr = prow * 64 + (((l16 >> 1) ^ ((quad * 4 + r) & 7)) * 8)
                               + (l16 & 1) * 4;
                *(uint2*)&Ps[padr] = pk;
            }
        }

        // O += P V (wave-local P rows: lgkmcnt ordering only, no barrier)
#pragma unroll
        for (int rb = 0; rb < 2; rb++) {
#pragma unroll
            for (int ks = 0; ks < 2; ks++) {
                const int fo = ks ? fo1 : fo0;
                const bf16x8 pf = *(const bf16x8*)&Ps[(wave * 32 + rb * 16 + l16) * 64 + fo];
#pragma unroll
                for (int j = 0; j < 4; j++) {
                    const bf16x8 vf = *(const bf16x8*)&Vs[(j * 16 + l16) * 64 + fo];
                    oacc[rb][j] = __builtin_amdgcn_mfma_f32_16x16x32_bf16(pf, vf, oacc[rb][j], 0, 0, 0);
                }
            }
        }

        if (it < 31) {                   // commit prefetch to other buffer
            *(uint4*)&smem[no + sA]        = kreg[0];
            *(uint4*)&smem[no + sB]        = kreg[1];
            *(uint4*)&smem[8192 + no + sA] = vreg[0];
            *(uint4*)&smem[8192 + no + sB] = vreg[1];
        }
    }

#pragma unroll
    for (int rb = 0; rb < 2; rb++)
#pragma unroll
        for (int r = 0; r < 4; r++) {
#pragma unroll
            for (int off = 1; off < 16; off <<= 1)
                lsum[rb][r] += __shfl_xor(lsum[rb][r], off, 64);
            lsum[rb][r] = 1.f / lsum[rb][r];
        }

    // epilogue: bf16 O into Ps (swizzled), then straight physical-chunk copy
    __syncthreads();
#pragma unroll
    for (int rb = 0; rb < 2; rb++)
#pragma unroll
        for (int j = 0; j < 4; j++)
#pragma unroll
            for (int r = 0; r < 4; r++) {
                const int row = wave * 32 + rb * 16 + quad * 4 + r;
                const int key = (quad * 4 + r) & 7;
                const int c   = j * 2 + (l16 >> 3);
                Ps[row * 64 + ((c ^ key) * 8) + (l16 & 7)] =
                    f2bf(oacc[rb][j][r] * lsum[rb][r]);
            }

    // copy-out: row = t>>1 is wave-local (wave w owns rows 32w..32w+31).
    // Ps physical chunk p holds logical chunk p^ (row&7); global expects
    // logical g8 at offset (g8^(qrow&7))*8 and qrow&7 == row&7 -> copy phys.
    const int row  = t >> 1;
    const int qrow = qtile * 128 + row;
    const int b = bh / H_, h = bh % H_;
    unsigned short* dst = Ao + (long)(b * S_ + qrow) * D_ + h * DK_;
#pragma unroll
    for (int i = 0; i < 4; i++) {
        const int p = (t & 1) * 4 + i;
        *(uint4*)(dst + p * 8) = *(const uint4*)&Ps[row * 64 + p * 8];
    }
}

// ---------------------------------------------------------------------------
// Output projection: Ao_sw bf16 @ Wo_sw -> fp32 d_out + bias. Tile 64x64,
// grid (64,12)=768 = 3/CU; launch_bounds(256,4) so all blocks resident.
// 4 waves 2x2 (wave 32x32), both operands async. Single-pass LDS epilogue.
// ---------------------------------------------------------------------------
__global__ __launch_bounds__(256, 4) void gemm_out(
    const unsigned short* __restrict__ A, const unsigned short* __restrict__ Wsw,
    const float* __restrict__ bias, float* __restrict__ Out)
{
    __shared__ __align__(16) unsigned short smem[8704];
    unsigned short* As = smem;           // [64][64] swizzled
    unsigned short* Bs = smem + 4096;    // [64][64] swizzled

    const int t    = threadIdx.x;
    const int wave = t >> 6;
    const int lane = t & 63;
    const int l16  = lane & 15;
    const int quad = lane >> 4;
    const int wm   = wave >> 1, wn = wave & 1;
    const int m0   = blockIdx.x * 64;
    const int n0   = blockIdx.y * 64;

    f32x4 acc[2][2];
#pragma unroll
    for (int s = 0; s < 2; s++)
#pragma unroll
        for (int j = 0; j < 2; j++) acc[s][j] = (f32x4){0.f, 0.f, 0.f, 0.f};

    const int lrow = lane >> 3;
    const int lcg  = lane & 7;

    for (int k0 = 0; k0 < D_; k0 += 64) {
        __syncthreads();
#pragma unroll
        for (int i = 0; i < 2; i++) {
            const int chunk = wave * 2 + i;
            async_cp16(A + (long)(m0 + chunk * 8 + lrow) * D_ + k0 + lcg * 8,
                       As + chunk * 512);
        }
#pragma unroll
        for (int i = 0; i < 2; i++) {
            const int chunk = wave * 2 + i;
            async_cp16(Wsw + (long)(n0 + chunk * 8 + lrow) * D_ + k0 + lcg * 8,
                       Bs + chunk * 512);
        }
        __syncthreads();
#pragma unroll
        for (int ks = 0; ks < 2; ks++) {
            const int cg = ks * 4 + quad;
            bf16x8 af[2], bf[2];
#pragma unroll
            for (int s = 0; s < 2; s++) {
                const int r = wm * 32 + s * 16 + l16;
                af[s] = *(const bf16x8*)&As[r * 64 + ((cg ^ (r & 7)) * 8)];
            }
#pragma unroll
            for (int j = 0; j < 2; j++) {
                const int r = wn * 32 + j * 16 + l16;
                bf[j] = *(const bf16x8*)&Bs[r * 64 + ((cg ^ (r & 7)) * 8)];
            }
#pragma unroll
            for (int s = 0; s < 2; s++)
#pragma unroll
                for (int j = 0; j < 2; j++)
                    acc[s][j] = __builtin_amdgcn_mfma_f32_16x16x32_bf16(af[s], bf[j], acc[s][j], 0, 0, 0);
        }
    }

    float bv[2];
#pragma unroll
    for (int j = 0; j < 2; j++) bv[j] = bias[n0 + wn * 32 + j * 16 + l16];

    __syncthreads();                     // done with As/Bs before reuse
    float* fl = (float*)smem;            // [64][67]
#pragma unroll
    for (int s = 0; s < 2; s++)
#pragma unroll
        for (int j = 0; j < 2; j++)
#pragma unroll
            for (int r = 0; r < 4; r++)
                fl[(wm * 32 + s * 16 + quad * 4 + r) * 67 + wn * 32 + j * 16 + l16] =
                    acc[s][j][r] + bv[j];
    __syncthreads();
    const int row = t >> 2, c0 = (t & 3) * 16;
#pragma unroll
    for (int i = 0; i < 4; i++) {
        const float4 v = *(const float4*)&fl[row * 67 + c0 + i * 4];
        *(float4*)(Out + (long)(m0 + row) * D_ + n0 + c0 + i * 4) = v;
    }
}

extern "C" void kernel_launch(void* const* d_in, const int* in_sizes, int n_in,
                              void* d_out, int out_size, void* d_ws, size_t ws_size,
                              hipStream_t stream) {
    const float* k_in = (const float*)d_in[0];
    const float* q_in = (const float*)d_in[1];
    const float* v_in = (const float*)d_in[2];
    // d_in[3] = mask: no-op per reference
    const float* wq = (const float*)d_in[4];
    const float* bq = (const float*)d_in[5];
    const float* wk = (const float*)d_in[6];
    const float* bk = (const float*)d_in[7];
    const float* wv = (const float*)d_in[8];
    const float* bv = (const float*)d_in[9];
    const float* wo = (const float*)d_in[10];
    const float* bo = (const float*)d_in[11];

    unsigned short* ws = (unsigned short*)d_ws;
    unsigned short* Wsw = ws;                          // 4*NW bf16 swizzled
    unsigned short* Qb  = Wsw + 4ll * NW_;             // NX bf16
    unsigned short* Kb  = Qb + (long)NX_;
    unsigned short* Vt  = Kb + (long)NX_;
    unsigned short* Xsw = Vt + (long)NX_;              // 3*NX (dead after qkv)
    unsigned short* Ao  = Xsw;                         // aliases Xsw

    CvtArgs ca;
    ca.s[0] = q_in; ca.s[1] = k_in; ca.s[2] = v_in;
    ca.s[3] = wq;   ca.s[4] = wk;   ca.s[5] = wv;  ca.s[6] = wo;
    cvt_all<<<dim3(2880), 256, 0, stream>>>(ca, Xsw, Wsw);

    QkvArgs qa;
    qa.bias[0] = bq; qa.bias[1] = bk; qa.bias[2] = bv;
    qa.out[0] = Qb;  qa.out[1] = Kb;  qa.out[2] = Vt;
    gemm_qkv<<<dim3(32, 18), 256, 0, stream>>>(qa, Xsw, Wsw);

    attn_kernel<<<dim3(384), 256, 0, stream>>>(Qb, Kb, Vt, Ao);

    gemm_out<<<dim3(64, 12), 256, 0, stream>>>(Ao, Wsw + 3ll * NW_, bo, (float*)d_out);
}

// Round 5
// 210.623 us; speedup vs baseline: 1.0721x; 1.0721x over previous
//
#include <hip/hip_runtime.h>
#include <hip/hip_bf16.h>

// MHA: B=2 S=2048 D=768 H=12 DK=64. fp32 in/out; bf16 MFMA internally.
#define B_  2
#define S_  2048
#define D_  768
#define H_  12
#define DK_ 64
#define NX_ (B_*S_*D_)      // 3145728 activation elements
#define NW_ (D_*D_)         // 589824 weight elements
#define CSC 0.18033688011112042f   // 0.125 * log2(e), baked into wq/bq

typedef __attribute__((ext_vector_type(8))) short  bf16x8;
typedef __attribute__((ext_vector_type(4))) float  f32x4;

__device__ __forceinline__ unsigned short f2bf(float f) {
    unsigned int u = __float_as_uint(f);
    u += 0x7fffu + ((u >> 16) & 1u);   // RNE
    return (unsigned short)(u >> 16);
}

// pack two fp32 -> two bf16 (+0x8000 then hi16) in 3 VALU ops
__device__ __forceinline__ unsigned pack_bf2(float a, float b) {
    const unsigned ua = __float_as_uint(a) + 0x8000u;
    const unsigned ub = __float_as_uint(b) + 0x8000u;
    return __builtin_amdgcn_perm(ub, ua, 0x07060302u);
}

__device__ __forceinline__ void async_cp16(const unsigned short* g,
                                           const unsigned short* lds_uniform_base) {
    __builtin_amdgcn_global_load_lds(
        (const __attribute__((address_space(1))) unsigned int*)(uintptr_t)g,
        (__attribute__((address_space(3))) unsigned int*)(unsigned int)(uintptr_t)lds_uniform_base,
        16, 0, 0);
}

// ---------------------------------------------------------------------------
// Fused fp32->bf16 cvt, xor-swizzled per 64-el k-block (group g8 -> g8^(n&7)).
// 16 elements/thread. 1D grid: 3*768 activation blocks + 4*144 weight blocks.
// ---------------------------------------------------------------------------
struct CvtArgs { const float* s[7]; };

__global__ __launch_bounds__(256) void cvt_all(CvtArgs a,
                                               unsigned short* __restrict__ Xsw,
                                               unsigned short* __restrict__ Wsw) {
    const int bx = blockIdx.x;
    int y, inner;
    if (bx < 2304) { y = bx / 768;             inner = bx % 768; }
    else           { y = 3 + (bx - 2304) / 144; inner = (bx - 2304) % 144; }
    const int idx = inner * 256 + threadIdx.x;
    const int n  = idx / 48;
    const int g2 = idx % 48;                  // 16-el group in row
    const float* src = a.s[y] + (long)n * D_ + g2 * 16;
    const float zs = (y == 3) ? CSC : 1.0f;
    unsigned short o[16];
#pragma unroll
    for (int i = 0; i < 4; i++) {
        const float4 f = *(const float4*)(src + i * 4);
        o[i*4+0] = f2bf(f.x*zs); o[i*4+1] = f2bf(f.y*zs);
        o[i*4+2] = f2bf(f.z*zs); o[i*4+3] = f2bf(f.w*zs);
    }
    unsigned short* dst = (y >= 3) ? (Wsw + (long)(y - 3) * NW_ + (long)n * D_)
                                   : (Xsw + (long)y * NX_ + (long)n * D_);
    const int key = n & 7;
#pragma unroll
    for (int h = 0; h < 2; h++) {
        const int g8 = g2 * 2 + h;
        const int kdst = (g8 >> 3) * 64 + (((g8 & 7) ^ key) * 8);
        *(uint4*)(dst + kdst) = *(const uint4*)&o[h * 8];
    }
}

// ---------------------------------------------------------------------------
// Fused QKV projection. grid(32, 18): y -> zz = y/6, nb = y%6. Tile 128x128,
// BK=64, 4 waves 2x2. Both operands async-staged from swizzled bf16 global.
// launch_bounds(256,3): all 576 blocks resident (no tail round).
// Outputs: Q/K [bh][s][dk]; V transposed+pi-permuted [bh][dk][s'].
// ---------------------------------------------------------------------------
struct QkvArgs { const float* bias[3]; unsigned short* out[3]; };

__global__ __launch_bounds__(256, 3) void gemm_qkv(QkvArgs args,
                                                   const unsigned short* __restrict__ Xsw,
                                                   const unsigned short* __restrict__ Wsw) {
    __shared__ __align__(16) unsigned short smem[17408];
    unsigned short* As = smem;           // [128][64] swizzled
    unsigned short* Bs = smem + 8192;    // [128][64] swizzled

    const int t    = threadIdx.x;
    const int wave = t >> 6;
    const int lane = t & 63;
    const int l16  = lane & 15;
    const int quad = lane >> 4;
    const int wm   = wave >> 1, wn = wave & 1;
    const int m0   = blockIdx.x * 128;
    const int zz   = blockIdx.y / 6;
    const int nb   = blockIdx.y % 6;
    const int n0   = nb * 128;

    const unsigned short* Ap = Xsw + (long)zz * NX_;
    const unsigned short* Wp = Wsw + (long)zz * NW_;

    f32x4 acc[4][4];
#pragma unroll
    for (int s = 0; s < 4; s++)
#pragma unroll
        for (int j = 0; j < 4; j++) acc[s][j] = (f32x4){0.f, 0.f, 0.f, 0.f};

    const int lrow = lane >> 3;
    const int lcg  = lane & 7;

    for (int k0 = 0; k0 < D_; k0 += 64) {
        __syncthreads();
#pragma unroll
        for (int i = 0; i < 4; i++) {
            const int chunk = wave * 4 + i;
            async_cp16(Ap + (long)(m0 + chunk * 8 + lrow) * D_ + k0 + lcg * 8,
                       As + chunk * 512);
        }
#pragma unroll
        for (int i = 0; i < 4; i++) {
            const int chunk = wave * 4 + i;
            async_cp16(Wp + (long)(n0 + chunk * 8 + lrow) * D_ + k0 + lcg * 8,
                       Bs + chunk * 512);
        }
        __syncthreads();
#pragma unroll
        for (int ks = 0; ks < 2; ks++) {
            const int cg = ks * 4 + quad;
            bf16x8 af[4], bf[4];
#pragma unroll
            for (int s = 0; s < 4; s++) {
                const int r = wm * 64 + s * 16 + l16;
                af[s] = *(const bf16x8*)&As[r * 64 + ((cg ^ (r & 7)) * 8)];
            }
#pragma unroll
            for (int j = 0; j < 4; j++) {
                const int r = wn * 64 + j * 16 + l16;
                bf[j] = *(const bf16x8*)&Bs[r * 64 + ((cg ^ (r & 7)) * 8)];
            }
#pragma unroll
            for (int s = 0; s < 4; s++)
#pragma unroll
                for (int j = 0; j < 4; j++)
                    acc[s][j] = __builtin_amdgcn_mfma_f32_16x16x32_bf16(af[s], bf[j], acc[s][j], 0, 0, 0);
        }
    }
    __syncthreads();

    const int b     = m0 >> 11;
    const int sbase = m0 & (S_ - 1);
    const float zs  = (zz == 0) ? CSC : 1.0f;
    float bv[4];
#pragma unroll
    for (int j = 0; j < 4; j++) bv[j] = args.bias[zz][n0 + wn * 64 + j * 16 + l16] * zs;

    if (zz < 2) {
        unsigned short* Ls = smem;       // [128][136]
#pragma unroll
        for (int s = 0; s < 4; s++)
#pragma unroll
            for (int j = 0; j < 4; j++)
#pragma unroll
                for (int r = 0; r < 4; r++)
                    Ls[(wm * 64 + s * 16 + quad * 4 + r) * 136 + wn * 64 + j * 16 + l16] =
                        f2bf(acc[s][j][r] + bv[j]);
        __syncthreads();
        const int row  = t >> 1;
        const int half = t & 1;
        unsigned short* Op = args.out[zz];
#pragma unroll
        for (int i = 0; i < 8; i++) {
            const int col  = half * 64 + i * 8;
            const int head = nb * 2 + half;
            const uint4 v = *(const uint4*)&Ls[row * 136 + col];
            *(uint4*)(Op + ((long)(b * H_ + head) * S_ + sbase + row) * DK_ + (col & 63)) = v;
        }
    } else {
        unsigned short* Ls = smem;       // [2][64][136]
#pragma unroll
        for (int s = 0; s < 4; s++)
#pragma unroll
            for (int j = 0; j < 4; j++)
#pragma unroll
                for (int r = 0; r < 4; r++) {
                    const int dk  = j * 16 + l16;
                    const int pos = wm * 64 + (quad * 4 + r) * 4 + s;   // pi-permute
                    Ls[wn * 8704 + dk * 136 + pos] = f2bf(acc[s][j][r] + bv[j]);
                }
        __syncthreads();
        const int rowIdx = t >> 1;
        const int hh = rowIdx >> 6, dk = rowIdx & 63;
        const int half = t & 1;
        unsigned short* Op = args.out[2];
#pragma unroll
        for (int i = 0; i < 8; i++) {
            const int col = half * 64 + i * 8;
            const uint4 v = *(const uint4*)&Ls[hh * 8704 + dk * 136 + col];
            const int head = nb * 2 + hh;
            *(uint4*)(Op + ((long)(b * H_ + head) * DK_ + dk) * S_ + sbase + col) = v;
        }
    }
}

// ---------------------------------------------------------------------------
// Flash attention v5: EXACT R7/v0 structure (proven 61 us: 64-row q-tiles,
// 4 waves x 16 rows, 768 blocks = 3/CU = 12 waves/CU, reg-prefetch rolling
// pointers, double-buffered K/V, 1 barrier/iter, pi-permuted P/V, no-max
// softmax) with ONE change: [64][64] XOR-swizzled K/V/P tiles (16B chunk ^=
// row&7) replacing the [64][72] padding. R4 verified this swizzle is correct
// and conflict-free (7.1M -> 74K conflict cycles); R4's regression came only
// from its occupancy/amortization restructure, which is reverted here.
// LDS: K0@0 K1@4096 V0@8192 V1@12288 Ps@16384 = 40 KB (3 blocks/CU).
// 1D grid, bh = bid%24: head pinned to one XCD L2 (FETCH 52->9.3 MB, free).
// ---------------------------------------------------------------------------
__global__ __launch_bounds__(256, 3) void attn_kernel(
    const unsigned short* __restrict__ Q, const unsigned short* __restrict__ K,
    const unsigned short* __restrict__ Vt, unsigned short* __restrict__ Ao)
{
    const int t    = threadIdx.x;
    const int wave = t >> 6;
    const int lane = t & 63;
    const int l16  = lane & 15;
    const int quad = lane >> 4;
    const int bid  = blockIdx.x;        // 768 blocks, 1D
    const int bh    = bid % 24;         // XCD = bid % 8 -> head-local L2
    const int qtile = bid / 24;         // 32 tiles of 64 rows

    const unsigned short* Qp = Q  + (long)bh * S_ * DK_;
    const unsigned short* Kp = K  + (long)bh * S_ * DK_;
    const unsigned short* Vp = Vt + (long)bh * DK_ * S_;

    __shared__ __align__(16) unsigned short smem[20480];   // 40 KB
    unsigned short* Ps = smem + 16384;

    // swizzle keys for fragment reads (row = *16 + l16 -> key = l16&7)
    const int fkey = l16 & 7;
    const int fo0  = ((quad ^ fkey) * 8);            // ks=0 chunk
    const int fo1  = (((4 + quad) ^ fkey) * 8);      // ks=1 chunk

    bf16x8 qfrag[2];
    {
        const long qoff = (long)(qtile * 64 + wave * 16 + l16) * DK_ + quad * 8;
        qfrag[0] = *(const bf16x8*)(Qp + qoff);
        qfrag[1] = *(const bf16x8*)(Qp + qoff + 32);
    }

    // staging: thread -> row t>>2 (0..63), chunks 2*(t&3), 2*(t&3)+1 (swizzled)
    const int srow = t >> 2;
    const int sc2  = t & 3;
    const int skey = srow & 7;
    const int sA   = srow * 64 + (((2 * sc2)     ^ skey) * 8);
    const int sB   = srow * 64 + (((2 * sc2 + 1) ^ skey) * 8);
    uint4 kreg[2], vreg[2];
    const unsigned short* gk = Kp + (long)srow * DK_ + sc2 * 16;
    const unsigned short* gv = Vp + (long)srow * S_ + sc2 * 16;
    kreg[0] = *(const uint4*)gk;  kreg[1] = *(const uint4*)(gk + 8);
    vreg[0] = *(const uint4*)gv;  vreg[1] = *(const uint4*)(gv + 8);
    gk += 64 * DK_;  gv += 64;
    *(uint4*)&smem[sA]        = kreg[0];
    *(uint4*)&smem[sB]        = kreg[1];
    *(uint4*)&smem[8192 + sA] = vreg[0];
    *(uint4*)&smem[8192 + sB] = vreg[1];

    f32x4 oacc[4];
#pragma unroll
    for (int j = 0; j < 4; j++) oacc[j] = (f32x4){0.f, 0.f, 0.f, 0.f};
    float lsum[4] = {0.f, 0.f, 0.f, 0.f};

    for (int it = 0; it < 32; ++it) {
        const int co = (it & 1) * 4096;          // current buffer offset
        const int no = 4096 - co;                // next buffer offset
        __syncthreads();                 // prev-iter commits visible
        const unsigned short* Ks = smem + co;
        const unsigned short* Vs = smem + 8192 + co;

        if (it < 31) {                   // prefetch next tile into registers
            kreg[0] = *(const uint4*)gk;  kreg[1] = *(const uint4*)(gk + 8);
            vreg[0] = *(const uint4*)gv;  vreg[1] = *(const uint4*)(gv + 8);
            gk += 64 * DK_;  gv += 64;
        }

        // S = Q K^T
        f32x4 sacc[4];
#pragma unroll
        for (int j = 0; j < 4; j++) sacc[j] = (f32x4){0.f, 0.f, 0.f, 0.f};
#pragma unroll
        for (int ks = 0; ks < 2; ks++) {
            const int fo = ks ? fo1 : fo0;
#pragma unroll
            for (int j = 0; j < 4; j++) {
                const bf16x8 bf = *(const bf16x8*)&Ks[(j * 16 + l16) * 64 + fo];
                sacc[j] = __builtin_amdgcn_mfma_f32_16x16x32_bf16(qfrag[ks], bf, sacc[j], 0, 0, 0);
            }
        }

        // p = exp2(s); packed b64 P-stores, pi-permuted cols, swizzled chunks
#pragma unroll
        for (int r = 0; r < 4; r++) {
            const float p0 = exp2f(sacc[0][r]);
            const float p1 = exp2f(sacc[1][r]);
            const float p2 = exp2f(sacc[2][r]);
            const float p3 = exp2f(sacc[3][r]);
            lsum[r] += (p0 + p1) + (p2 + p3);
            uint2 pk = {pack_bf2(p0, p1), pack_bf2(p2, p3)};
            const int prow = wave * 16 + quad * 4 + r;
            *(uint2*)&Ps[prow * 64 + (((l16 >> 1) ^ (prow & 7)) * 8) + (l16 & 1) * 4] = pk;
        }

        // O += P V (wave-local P rows: lgkmcnt ordering only, no barrier)
#pragma unroll
        for (int ks = 0; ks < 2; ks++) {
            const int fo = ks ? fo1 : fo0;
            const bf16x8 pf = *(const bf16x8*)&Ps[(wave * 16 + l16) * 64 + fo];
#pragma unroll
            for (int j = 0; j < 4; j++) {
                const bf16x8 vf = *(const bf16x8*)&Vs[(j * 16 + l16) * 64 + fo];
                oacc[j] = __builtin_amdgcn_mfma_f32_16x16x32_bf16(pf, vf, oacc[j], 0, 0, 0);
            }
        }

        if (it < 31) {                   // commit prefetch to other buffer
            *(uint4*)&smem[no + sA]        = kreg[0];
            *(uint4*)&smem[no + sB]        = kreg[1];
            *(uint4*)&smem[8192 + no + sA] = vreg[0];
            *(uint4*)&smem[8192 + no + sB] = vreg[1];
        }
    }

#pragma unroll
    for (int r = 0; r < 4; r++) {
#pragma unroll
        for (int off = 1; off < 16; off <<= 1)
            lsum[r] += __shfl_xor(lsum[r], off, 64);
        lsum[r] = 1.f / lsum[r];
    }

    // epilogue: bf16 O into Ps (swizzled), then straight physical-chunk copy.
    // Ps physical chunk p of row holds logical chunk p^(row&7); the global
    // swizzle key is qrow&7 == row&7, so copy-out is a physical copy.
    __syncthreads();
#pragma unroll
    for (int j = 0; j < 4; j++)
#pragma unroll
        for (int r = 0; r < 4; r++) {
            const int row = wave * 16 + quad * 4 + r;
            const int c   = j * 2 + (l16 >> 3);
            Ps[row * 64 + ((c ^ (row & 7)) * 8) + (l16 & 7)] =
                f2bf(oacc[j][r] * lsum[r]);
        }

    const int b = bh / H_, h = bh % H_;
    const int row = t >> 2;             // wave-local rows: no barrier needed
    const int p0  = (t & 3) * 2;
    const int qrow = qtile * 64 + row;
    unsigned short* dst = Ao + (long)(b * S_ + qrow) * D_ + h * DK_;
    *(uint4*)(dst + p0 * 8)       = *(const uint4*)&Ps[row * 64 + p0 * 8];
    *(uint4*)(dst + (p0 + 1) * 8) = *(const uint4*)&Ps[row * 64 + (p0 + 1) * 8];
}

// ---------------------------------------------------------------------------
// Output projection: Ao_sw bf16 @ Wo_sw -> fp32 d_out + bias. Tile 64x64,
// grid (64,12)=768 = 3/CU; launch_bounds(256,4) so all blocks resident.
// 4 waves 2x2 (wave 32x32), both operands async. Single-pass LDS epilogue.
// ---------------------------------------------------------------------------
__global__ __launch_bounds__(256, 4) void gemm_out(
    const unsigned short* __restrict__ A, const unsigned short* __restrict__ Wsw,
    const float* __restrict__ bias, float* __restrict__ Out)
{
    __shared__ __align__(16) unsigned short smem[8704];
    unsigned short* As = smem;           // [64][64] swizzled
    unsigned short* Bs = smem + 4096;    // [64][64] swizzled

    const int t    = threadIdx.x;
    const int wave = t >> 6;
    const int lane = t & 63;
    const int l16  = lane & 15;
    const int quad = lane >> 4;
    const int wm   = wave >> 1, wn = wave & 1;
    const int m0   = blockIdx.x * 64;
    const int n0   = blockIdx.y * 64;

    f32x4 acc[2][2];
#pragma unroll
    for (int s = 0; s < 2; s++)
#pragma unroll
        for (int j = 0; j < 2; j++) acc[s][j] = (f32x4){0.f, 0.f, 0.f, 0.f};

    const int lrow = lane >> 3;
    const int lcg  = lane & 7;

    for (int k0 = 0; k0 < D_; k0 += 64) {
        __syncthreads();
#pragma unroll
        for (int i = 0; i < 2; i++) {
            const int chunk = wave * 2 + i;
            async_cp16(A + (long)(m0 + chunk * 8 + lrow) * D_ + k0 + lcg * 8,
                       As + chunk * 512);
        }
#pragma unroll
        for (int i = 0; i < 2; i++) {
            const int chunk = wave * 2 + i;
            async_cp16(Wsw + (long)(n0 + chunk * 8 + lrow) * D_ + k0 + lcg * 8,
                       Bs + chunk * 512);
        }
        __syncthreads();
#pragma unroll
        for (int ks = 0; ks < 2; ks++) {
            const int cg = ks * 4 + quad;
            bf16x8 af[2], bf[2];
#pragma unroll
            for (int s = 0; s < 2; s++) {
                const int r = wm * 32 + s * 16 + l16;
                af[s] = *(const bf16x8*)&As[r * 64 + ((cg ^ (r & 7)) * 8)];
            }
#pragma unroll
            for (int j = 0; j < 2; j++) {
                const int r = wn * 32 + j * 16 + l16;
                bf[j] = *(const bf16x8*)&Bs[r * 64 + ((cg ^ (r & 7)) * 8)];
            }
#pragma unroll
            for (int s = 0; s < 2; s++)
#pragma unroll
                for (int j = 0; j < 2; j++)
                    acc[s][j] = __builtin_amdgcn_mfma_f32_16x16x32_bf16(af[s], bf[j], acc[s][j], 0, 0, 0);
        }
    }

    float bv[2];
#pragma unroll
    for (int j = 0; j < 2; j++) bv[j] = bias[n0 + wn * 32 + j * 16 + l16];

    __syncthreads();                     // done with As/Bs before reuse
    float* fl = (float*)smem;            // [64][67]
#pragma unroll
    for (int s = 0; s < 2; s++)
#pragma unroll
        for (int j = 0; j < 2; j++)
#pragma unroll
            for (int r = 0; r < 4; r++)
                fl[(wm * 32 + s * 16 + quad * 4 + r) * 67 + wn * 32 + j * 16 + l16] =
                    acc[s][j][r] + bv[j];
    __syncthreads();
    const int row = t >> 2, c0 = (t & 3) * 16;
#pragma unroll
    for (int i = 0; i < 4; i++) {
        const float4 v = *(const float4*)&fl[row * 67 + c0 + i * 4];
        *(float4*)(Out + (long)(m0 + row) * D_ + n0 + c0 + i * 4) = v;
    }
}

extern "C" void kernel_launch(void* const* d_in, const int* in_sizes, int n_in,
                              void* d_out, int out_size, void* d_ws, size_t ws_size,
                              hipStream_t stream) {
    const float* k_in = (const float*)d_in[0];
    const float* q_in = (const float*)d_in[1];
    const float* v_in = (const float*)d_in[2];
    // d_in[3] = mask: no-op per reference
    const float* wq = (const float*)d_in[4];
    const float* bq = (const float*)d_in[5];
    const float* wk = (const float*)d_in[6];
    const float* bk = (const float*)d_in[7];
    const float* wv = (const float*)d_in[8];
    const float* bv = (const float*)d_in[9];
    const float* wo = (const float*)d_in[10];
    const float* bo = (const float*)d_in[11];

    unsigned short* ws = (unsigned short*)d_ws;
    unsigned short* Wsw = ws;                          // 4*NW bf16 swizzled
    unsigned short* Qb  = Wsw + 4ll * NW_;             // NX bf16
    unsigned short* Kb  = Qb + (long)NX_;
    unsigned short* Vt  = Kb + (long)NX_;
    unsigned short* Xsw = Vt + (long)NX_;              // 3*NX (dead after qkv)
    unsigned short* Ao  = Xsw;                         // aliases Xsw

    CvtArgs ca;
    ca.s[0] = q_in; ca.s[1] = k_in; ca.s[2] = v_in;
    ca.s[3] = wq;   ca.s[4] = wk;   ca.s[5] = wv;  ca.s[6] = wo;
    cvt_all<<<dim3(2880), 256, 0, stream>>>(ca, Xsw, Wsw);

    QkvArgs qa;
    qa.bias[0] = bq; qa.bias[1] = bk; qa.bias[2] = bv;
    qa.out[0] = Qb;  qa.out[1] = Kb;  qa.out[2] = Vt;
    gemm_qkv<<<dim3(32, 18), 256, 0, stream>>>(qa, Xsw, Wsw);

    attn_kernel<<<dim3(768), 256, 0, stream>>>(Qb, Kb, Vt, Ao);

    gemm_out<<<dim3(64, 12), 256, 0, stream>>>(Ao, Wsw + 3ll * NW_, bo, (float*)d_out);
}